// Round 1
// baseline (409.373 us; speedup 1.0000x reference)
//
#include <hip/hip_runtime.h>
#include <math.h>

// Problem constants
#define D_ELEMS 25088   // C*H*W = 512*7*7
#define D4      6272    // D_ELEMS / 4
#define D2      12544   // D_ELEMS / 2
#define N_MEM   2000
#define B_KEYS  32
#define PI_2F   1.570795f   // 3.14159 / 2, matches reference
#define EPSF    1e-8f

// ws layout (floats):
//   [0, 64000)          dots[n][b]  (later overwritten in-place with softmax w)
//   [64000, 66000)      m_norm2[n]
//   [66048, +ns*802816) partial[s][b][d]

__global__ __launch_bounds__(256) void k_zero(float* __restrict__ ws) {
    ws[blockIdx.x * 256 + threadIdx.x] = 0.f;   // grid 258*256 == 66048 exactly
}

// dots[n][b] = sum_d key[b][d]*mem[n][d]; m_norm2[n] = sum_d mem[n][d]^2
// grid: 250 n-tiles (NT=8) x 2 d-halves. block: 256 thr = 4 waves, wave bg
// handles keys [bg*8, bg*8+8). Each lane covers a strided f4 d-slice.
__global__ __launch_bounds__(256) void k_dots(const float* __restrict__ key,
                                              const float* __restrict__ mem,
                                              float* __restrict__ dots,
                                              float* __restrict__ mnorm2) {
    const int nb   = blockIdx.x >> 1;
    const int s    = blockIdx.x & 1;
    const int n0   = nb * 8;
    const int bg   = threadIdx.x >> 6;
    const int lane = threadIdx.x & 63;

    const float4* K4 = (const float4*)key;
    const float4* M4 = (const float4*)mem;

    float acc[8][8];   // [n_local][b_local]
#pragma unroll
    for (int j = 0; j < 8; ++j)
#pragma unroll
        for (int i = 0; i < 8; ++i) acc[j][i] = 0.f;
    float msq[8] = {0.f,0.f,0.f,0.f,0.f,0.f,0.f,0.f};

    const int c0 = s * 49;                 // 49 chunks of 64 f4 per d-half
    for (int c = 0; c < 49; ++c) {
        const int d4 = (c0 + c) * 64 + lane;
        float4 kf[8], mf[8];
#pragma unroll
        for (int i = 0; i < 8; ++i) kf[i] = K4[(bg * 8 + i) * D4 + d4];
#pragma unroll
        for (int j = 0; j < 8; ++j) mf[j] = M4[(n0 + j) * D4 + d4];
#pragma unroll
        for (int j = 0; j < 8; ++j) {
#pragma unroll
            for (int i = 0; i < 8; ++i) {
                acc[j][i] += mf[j].x * kf[i].x + mf[j].y * kf[i].y
                           + mf[j].z * kf[i].z + mf[j].w * kf[i].w;
            }
        }
        if (bg == 0) {
#pragma unroll
            for (int j = 0; j < 8; ++j)
                msq[j] += mf[j].x * mf[j].x + mf[j].y * mf[j].y
                        + mf[j].z * mf[j].z + mf[j].w * mf[j].w;
        }
    }

    // stage 1: butterfly over lane bits 3..5 -> lanes sharing (lane&7) summed
#pragma unroll
    for (int off = 8; off < 64; off <<= 1)
#pragma unroll
        for (int j = 0; j < 8; ++j)
#pragma unroll
            for (int i = 0; i < 8; ++i)
                acc[j][i] += __shfl_xor(acc[j][i], off, 64);

    __shared__ float red[4][8][65];
    if (lane < 8) {
#pragma unroll
        for (int j = 0; j < 8; ++j)
#pragma unroll
            for (int i = 0; i < 8; ++i)
                red[bg][lane][j * 8 + i] = acc[j][i];
    }
    __syncthreads();

    // lane j owns (n_local = j>>3, b_local = j&7)
    float ssum = red[bg][0][lane];
#pragma unroll
    for (int i = 1; i < 8; ++i) ssum += red[bg][i][lane];
    atomicAdd(&dots[(n0 + (lane >> 3)) * B_KEYS + bg * 8 + (lane & 7)], ssum);

    if (bg == 0) {
#pragma unroll
        for (int off = 1; off < 64; off <<= 1)
#pragma unroll
            for (int j = 0; j < 8; ++j)
                msq[j] += __shfl_xor(msq[j], off, 64);
        if (lane == 0) {
#pragma unroll
            for (int j = 0; j < 8; ++j) atomicAdd(&mnorm2[n0 + j], msq[j]);
        }
    }
}

// per-b: k_norm, cos -> tan -> softmax over n. Writes w in-place into dots
// column b (each block touches only its own column).
__global__ __launch_bounds__(256) void k_softmax(const float* __restrict__ key,
                                                 const float* __restrict__ dots,
                                                 const float* __restrict__ mnorm2,
                                                 float* __restrict__ w) {
    const int b   = blockIdx.x;
    const int tid = threadIdx.x;
    __shared__ float sred[256];
    __shared__ float xbuf[N_MEM];

    const float4* K4 = (const float4*)(key + (size_t)b * D_ELEMS);
    float ks = 0.f;
    for (int i = tid; i < D4; i += 256) {
        float4 kf = K4[i];
        ks += kf.x * kf.x + kf.y * kf.y + kf.z * kf.z + kf.w * kf.w;
    }
    sred[tid] = ks;
    __syncthreads();
    for (int o = 128; o; o >>= 1) {
        if (tid < o) sred[tid] += sred[tid + o];
        __syncthreads();
    }
    const float knorm = fmaxf(sqrtf(sred[0]), EPSF);
    __syncthreads();

    float mx = -1e30f;
    for (int n = tid; n < N_MEM; n += 256) {
        float mn   = fmaxf(sqrtf(mnorm2[n]), EPSF);
        float cosv = dots[n * B_KEYS + b] / (knorm * mn);
        float x    = tanf(cosv * PI_2F);
        xbuf[n] = x;
        mx = fmaxf(mx, x);
    }
    sred[tid] = mx;
    __syncthreads();
    for (int o = 128; o; o >>= 1) {
        if (tid < o) sred[tid] = fmaxf(sred[tid], sred[tid + o]);
        __syncthreads();
    }
    mx = sred[0];
    __syncthreads();

    float sm = 0.f;
    for (int n = tid; n < N_MEM; n += 256) sm += expf(xbuf[n] - mx);
    sred[tid] = sm;
    __syncthreads();
    for (int o = 128; o; o >>= 1) {
        if (tid < o) sred[tid] += sred[tid + o];
        __syncthreads();
    }
    const float inv = 1.f / sred[0];
    __syncthreads();

    for (int n = tid; n < N_MEM; n += 256)
        w[n * B_KEYS + b] = expf(xbuf[n] - mx) * inv;
}

// partial[s][b][d] = sum_{n in chunk s} w[n][b] * mem[n][d]
// grid: 98 d-blocks x ns n-splits; block 128 thr, each owns one float2 column,
// 32 b-accumulator pairs. w staged in LDS tiles of 128 n (broadcast reads).
__global__ __launch_bounds__(128) void k_read(const float* __restrict__ mem,
                                              const float* __restrict__ w,
                                              float* __restrict__ partial,
                                              int nPerS) {
    const int db = blockIdx.x % 98;
    const int s  = blockIdx.x / 98;
    const int n0 = s * nPerS;
    const int d2 = db * 128 + threadIdx.x;    // float2 column, < 12544

    const float2* M2 = (const float2*)mem;
    __shared__ float wls[128 * B_KEYS];       // 16 KB

    float accx[B_KEYS], accy[B_KEYS];
#pragma unroll
    for (int b = 0; b < B_KEYS; ++b) { accx[b] = 0.f; accy[b] = 0.f; }

    for (int t0 = 0; t0 < nPerS; t0 += 128) {
        const int tn = min(128, nPerS - t0);
        __syncthreads();
        for (int i = threadIdx.x; i < tn * B_KEYS; i += 128)
            wls[i] = w[(n0 + t0) * B_KEYS + i];
        __syncthreads();
        for (int nn = 0; nn < tn; ++nn) {
            const float2 mv = M2[(size_t)(n0 + t0 + nn) * D2 + d2];
            const float* wn = wls + nn * B_KEYS;
#pragma unroll
            for (int b = 0; b < B_KEYS; ++b) {
                const float wv = wn[b];
                accx[b] += wv * mv.x;
                accy[b] += wv * mv.y;
            }
        }
    }

    float2* P2 = (float2*)partial;
#pragma unroll
    for (int b = 0; b < B_KEYS; ++b)
        P2[(size_t)(s * B_KEYS + b) * D2 + d2] = make_float2(accx[b], accy[b]);
}

__global__ __launch_bounds__(256) void k_finish(const float* __restrict__ partial,
                                                float* __restrict__ out, int ns) {
    const int i = blockIdx.x * 256 + threadIdx.x;   // grid 3136*256 == 802816
    float sum = 0.f;
    for (int s = 0; s < ns; ++s) sum += partial[(size_t)s * (B_KEYS * D_ELEMS) + i];
    out[i] = sum;
}

extern "C" void kernel_launch(void* const* d_in, const int* in_sizes, int n_in,
                              void* d_out, int out_size, void* d_ws, size_t ws_size,
                              hipStream_t stream) {
    (void)in_sizes; (void)n_in; (void)out_size;
    const float* key = (const float*)d_in[0];
    const float* mem = (const float*)d_in[1];
    float* out = (float*)d_out;
    float* ws  = (float*)d_ws;

    float* dots   = ws;            // 64000 floats
    float* mnorm2 = ws + 64000;    // 2000 floats
    float* part   = ws + 66048;    // ns * 802816 floats

    int ns = 16;   // n-splits for k_read; shrink if ws is small (all divide 2000)
    while (ns > 1 && (size_t)(66048 + (size_t)ns * 802816) * 4 > ws_size) ns >>= 1;
    const int nPerS = N_MEM / ns;

    k_zero   <<<258, 256, 0, stream>>>(ws);
    k_dots   <<<500, 256, 0, stream>>>(key, mem, dots, mnorm2);
    k_softmax<<<B_KEYS, 256, 0, stream>>>(key, dots, mnorm2, dots);
    k_read   <<<98 * ns, 128, 0, stream>>>(mem, dots, part, nPerS);
    k_finish <<<3136, 256, 0, stream>>>(part, out, ns);
}